// Round 2
// baseline (308.508 us; speedup 1.0000x reference)
//
#include <hip/hip_runtime.h>

#define SEQ   2048
#define DIM   64
#define NB    2
#define NH    16
#define BQ    64
#define BK    64
#define PADK  72   /* 144 B rows: 16B-aligned for b128 LDS reads */
#define NKT   (SEQ / BK)

typedef float f32x4  __attribute__((ext_vector_type(4)));
typedef short bf16x8 __attribute__((ext_vector_type(8)));
typedef short s16x4  __attribute__((ext_vector_type(4)));

// log2(e) / sqrt(64): folded into Q so logits come out in log2 domain
#define QSCALE 0.18033688011112042f

__device__ __forceinline__ short f2bf(float x) {
    unsigned u = __float_as_uint(x);
    return (short)((u + 0x7FFFu + ((u >> 16) & 1u)) >> 16);
}
__device__ __forceinline__ float bf2f(short s) {
    return __uint_as_float(((unsigned)(unsigned short)s) << 16);
}

// 16x32 MFMA operand fragment (split-4 k-mapping) from row-major LDS row.
// Same mapping used for A and B of every MFMA -> any k-permutation cancels.
__device__ __forceinline__ bf16x8 ldfrag(const short* rowptr, int kbase) {
    s16x4 lo = *reinterpret_cast<const s16x4*>(rowptr + kbase);
    s16x4 hi = *reinterpret_cast<const s16x4*>(rowptr + kbase + 16);
    bf16x8 f;
    f[0] = lo[0]; f[1] = lo[1]; f[2] = lo[2]; f[3] = lo[3];
    f[4] = hi[0]; f[5] = hi[1]; f[6] = hi[2]; f[7] = hi[3];
    return f;
}

__global__ __launch_bounds__(256, 4)
void sdpa_fused_kernel(const float* __restrict__ Qp, const float* __restrict__ Kp,
                       const float* __restrict__ Vp, const int* __restrict__ Mp,
                       float* __restrict__ Op, float* __restrict__ Pp)
{
    __shared__ short Qs[BQ][PADK];
    __shared__ short Ks[BK][PADK];
    __shared__ short Vt[DIM][PADK];   // V transposed: [d][key]
    __shared__ short Ps[BQ][PADK];

    const int tid  = (int)threadIdx.x;
    const int lane = tid & 63;
    const int w    = tid >> 6;            // wave 0..3, owns q-rows w*16..w*16+15
    const int mrow = lane & 15;           // M/N index within 16
    const int kgrp = (lane >> 4) << 2;    // k-group base: 0,4,8,12

    const int qt = (int)blockIdx.x;
    const int bh = (int)blockIdx.y;

    const size_t headoff = (size_t)bh * SEQ * DIM;
    const float* Qg = Qp + headoff + (size_t)qt * BQ * DIM;
    const float* Kg = Kp + headoff;
    const float* Vg = Vp + headoff;
    const int*   Mg = Mp + (size_t)(bh / NH) * SEQ;
    float*       Og = Op + headoff + (size_t)qt * BQ * DIM;
    float*       Pg = Pp + ((size_t)bh * SEQ + (size_t)qt * BQ) * SEQ;

    const int r0 = tid >> 4;
    const int c0 = (tid & 15) << 2;

    // ---- stage Q tile (f32 -> bf16, scale folded in) ----
    #pragma unroll
    for (int i = 0; i < 4; ++i) {
        const int row = r0 + (i << 4);
        const float4 v = *reinterpret_cast<const float4*>(Qg + row * DIM + c0);
        s16x4 s;
        s[0] = f2bf(v.x * QSCALE); s[1] = f2bf(v.y * QSCALE);
        s[2] = f2bf(v.z * QSCALE); s[3] = f2bf(v.w * QSCALE);
        *reinterpret_cast<s16x4*>(&Qs[row][c0]) = s;
    }
    __syncthreads();

    const bf16x8 qf0 = ldfrag(&Qs[w * 16 + mrow][0], kgrp);
    const bf16x8 qf1 = ldfrag(&Qs[w * 16 + mrow][0], 32 + kgrp);

    // ================= pass 1: l[row] = sum_k exp(s), unmasked only =================
    float lsum[4] = {0.f, 0.f, 0.f, 0.f};

    for (int kt = 0; kt < NKT; ++kt) {
        __syncthreads();
        {
            const float* src = Kg + (size_t)kt * BK * DIM;
            #pragma unroll
            for (int i = 0; i < 4; ++i) {
                const int row = r0 + (i << 4);
                const float4 v = *reinterpret_cast<const float4*>(src + row * DIM + c0);
                s16x4 s;
                s[0] = f2bf(v.x); s[1] = f2bf(v.y); s[2] = f2bf(v.z); s[3] = f2bf(v.w);
                *reinterpret_cast<s16x4*>(&Ks[row][c0]) = s;
            }
        }
        __syncthreads();

        const int k0 = kt * BK;
        #pragma unroll
        for (int t = 0; t < 4; ++t) {
            const bf16x8 kf0 = ldfrag(&Ks[t * 16 + mrow][0], kgrp);
            const bf16x8 kf1 = ldfrag(&Ks[t * 16 + mrow][0], 32 + kgrp);
            f32x4 acc = {0.f, 0.f, 0.f, 0.f};
            acc = __builtin_amdgcn_mfma_f32_16x16x32_bf16(qf0, kf0, acc, 0, 0, 0);
            acc = __builtin_amdgcn_mfma_f32_16x16x32_bf16(qf1, kf1, acc, 0, 0, 0);
            const float mz = Mg[k0 + t * 16 + mrow] ? 0.f : 1.f;
            #pragma unroll
            for (int r = 0; r < 4; ++r)
                lsum[r] += mz * __builtin_amdgcn_exp2f(acc[r]);
        }
    }

    float rinv[4];
    #pragma unroll
    for (int r = 0; r < 4; ++r) {
        float v = lsum[r];
        v += __shfl_xor(v, 1);
        v += __shfl_xor(v, 2);
        v += __shfl_xor(v, 4);
        v += __shfl_xor(v, 8);
        rinv[r] = 1.0f / v;
    }

    // ================= pass 2: P tile -> LDS(bf16) -> coalesced write; O += P V ====
    f32x4 oacc[4];
    #pragma unroll
    for (int n = 0; n < 4; ++n) {
        oacc[n][0] = 0.f; oacc[n][1] = 0.f; oacc[n][2] = 0.f; oacc[n][3] = 0.f;
    }

    const int prow = tid >> 2;          // cooperative P-writer: row 0..63
    const int pc   = (tid & 3) << 4;    // col base 0/16/32/48

    for (int kt = 0; kt < NKT; ++kt) {
        __syncthreads();   // everyone done with Ks/Vt/Ps of previous iter
        {
            const float* src = Kg + (size_t)kt * BK * DIM;
            #pragma unroll
            for (int i = 0; i < 4; ++i) {
                const int row = r0 + (i << 4);
                const float4 v = *reinterpret_cast<const float4*>(src + row * DIM + c0);
                s16x4 s;
                s[0] = f2bf(v.x); s[1] = f2bf(v.y); s[2] = f2bf(v.z); s[3] = f2bf(v.w);
                *reinterpret_cast<s16x4*>(&Ks[row][c0]) = s;
            }
            const float* vsrc = Vg + (size_t)kt * BK * DIM;
            #pragma unroll
            for (int i = 0; i < 4; ++i) {
                const int key = r0 + (i << 4);
                const float4 v = *reinterpret_cast<const float4*>(vsrc + key * DIM + c0);
                Vt[c0 + 0][key] = f2bf(v.x);
                Vt[c0 + 1][key] = f2bf(v.y);
                Vt[c0 + 2][key] = f2bf(v.z);
                Vt[c0 + 3][key] = f2bf(v.w);
            }
        }
        __syncthreads();

        const int k0 = kt * BK;
        #pragma unroll
        for (int t = 0; t < 4; ++t) {
            const bf16x8 kf0 = ldfrag(&Ks[t * 16 + mrow][0], kgrp);
            const bf16x8 kf1 = ldfrag(&Ks[t * 16 + mrow][0], 32 + kgrp);
            f32x4 acc = {0.f, 0.f, 0.f, 0.f};
            acc = __builtin_amdgcn_mfma_f32_16x16x32_bf16(qf0, kf0, acc, 0, 0, 0);
            acc = __builtin_amdgcn_mfma_f32_16x16x32_bf16(qf1, kf1, acc, 0, 0, 0);
            const float mz = Mg[k0 + t * 16 + mrow] ? 0.f : 1.f;
            #pragma unroll
            for (int r = 0; r < 4; ++r) {
                const float p = mz * __builtin_amdgcn_exp2f(acc[r]) * rinv[r];
                Ps[w * 16 + kgrp + r][t * 16 + mrow] = f2bf(p);
            }
        }
        __syncthreads();   // Ps visible to all waves

        // ---- coalesced P tile write: thread -> 64B run, 4 threads -> 256B row run
        {
            float* dst = Pg + (size_t)prow * SEQ + k0 + pc;
            const short* srcrow = &Ps[prow][pc];
            #pragma unroll
            for (int h = 0; h < 2; ++h) {
                const bf16x8 v = *reinterpret_cast<const bf16x8*>(srcrow + h * 8);
                float4 f0, f1;
                f0.x = bf2f(v[0]); f0.y = bf2f(v[1]); f0.z = bf2f(v[2]); f0.w = bf2f(v[3]);
                f1.x = bf2f(v[4]); f1.y = bf2f(v[5]); f1.z = bf2f(v[6]); f1.w = bf2f(v[7]);
                *reinterpret_cast<float4*>(dst + h * 8)     = f0;
                *reinterpret_cast<float4*>(dst + h * 8 + 4) = f1;
            }
        }

        // ---- O += P V
        const bf16x8 pf0 = ldfrag(&Ps[w * 16 + mrow][0], kgrp);
        const bf16x8 pf1 = ldfrag(&Ps[w * 16 + mrow][0], 32 + kgrp);
        #pragma unroll
        for (int n = 0; n < 4; ++n) {
            const bf16x8 vf0 = ldfrag(&Vt[n * 16 + mrow][0], kgrp);
            const bf16x8 vf1 = ldfrag(&Vt[n * 16 + mrow][0], 32 + kgrp);
            oacc[n] = __builtin_amdgcn_mfma_f32_16x16x32_bf16(pf0, vf0, oacc[n], 0, 0, 0);
            oacc[n] = __builtin_amdgcn_mfma_f32_16x16x32_bf16(pf1, vf1, oacc[n], 0, 0, 0);
        }
    }

    #pragma unroll
    for (int n = 0; n < 4; ++n) {
        #pragma unroll
        for (int r = 0; r < 4; ++r)
            Og[(size_t)(w * 16 + kgrp + r) * DIM + n * 16 + mrow] = oacc[n][r];
    }
}

extern "C" void kernel_launch(void* const* d_in, const int* in_sizes, int n_in,
                              void* d_out, int out_size, void* d_ws, size_t ws_size,
                              hipStream_t stream) {
    const float* Q = (const float*)d_in[0];
    const float* K = (const float*)d_in[1];
    const float* V = (const float*)d_in[2];
    const int*   M = (const int*)d_in[3];
    float* O = (float*)d_out;
    float* P = O + (size_t)NB * NH * SEQ * DIM;   // weights follow output

    dim3 grid(SEQ / BQ, NB * NH);
    sdpa_fused_kernel<<<grid, dim3(256, 1, 1), 0, stream>>>(Q, K, V, M, O, P);
}

// Round 4
// 251.346 us; speedup vs baseline: 1.2274x; 1.2274x over previous
//
#include <hip/hip_runtime.h>

#define SEQ   2048
#define DIM   64
#define NB    2
#define NH    16
#define NHEAD (NB * NH)
#define BQ    64
#define BK    64
#define NKT   (SEQ / BK)
#define PADK  72
#define QSCALE 0.18033688011112042f  /* log2(e)/sqrt(64) */

typedef float  f32x4  __attribute__((ext_vector_type(4)));
typedef short  bf16x8 __attribute__((ext_vector_type(8)));
typedef short  s16x4  __attribute__((ext_vector_type(4)));
typedef unsigned short u16;
typedef u16    u16x8  __attribute__((ext_vector_type(8)));

__device__ __forceinline__ short f2bf(float x) {
    unsigned u = __float_as_uint(x);
    return (short)((u + 0x7FFFu + ((u >> 16) & 1u)) >> 16);
}

// fragment from padded (non-swizzled) LDS row: elements {kbase.., kbase+16..}
__device__ __forceinline__ bf16x8 ldfrag_pad(const short* rowptr, int kbase) {
    s16x4 lo = *reinterpret_cast<const s16x4*>(rowptr + kbase);
    s16x4 hi = *reinterpret_cast<const s16x4*>(rowptr + kbase + 16);
    bf16x8 f;
    f[0] = lo[0]; f[1] = lo[1]; f[2] = lo[2]; f[3] = lo[3];
    f[4] = hi[0]; f[5] = hi[1]; f[6] = hi[2]; f[7] = hi[3];
    return f;
}

// fragment from linear [64][64] bf16 tile stored with per-row XOR swizzle:
// stored_byte[b] = plain_byte[b ^ ((row&7)<<4)].  kbase semantics IDENTICAL
// to ldfrag_pad: elements {kbase..kbase+3, kbase+16..kbase+19}.
__device__ __forceinline__ bf16x8 ldfrag_swz(const u16* tile, int row, int kbase) {
    const char* rp = (const char*)(tile + row * 64);
    const int sw = (row & 7) << 4;
    s16x4 lo = *reinterpret_cast<const s16x4*>(rp + (((kbase << 1)     ) ^ sw));
    s16x4 hi = *reinterpret_cast<const s16x4*>(rp + (((kbase << 1) + 32) ^ sw));
    bf16x8 f;
    f[0] = lo[0]; f[1] = lo[1]; f[2] = lo[2]; f[3] = lo[3];
    f[4] = hi[0]; f[5] = hi[1]; f[6] = hi[2]; f[7] = hi[3];
    return f;
}

// ---------- pre-kernel: K f32 -> bf16, tiled + XOR-swizzled ----------
__global__ __launch_bounds__(256)
void conv_k_kernel(const float* __restrict__ K, u16* __restrict__ Kp)
{
    const int idx = (int)blockIdx.x * 256 + (int)threadIdx.x;  // < NHEAD*NKT*64*8
    const int u  = idx & 7;
    const int r  = (idx >> 3) & 63;
    const int kt = (idx >> 9) & 31;
    const int h  = idx >> 14;
    const int d0 = ((u ^ (r & 7)) << 3);
    const float* src = K + (((size_t)h * SEQ + (size_t)kt * 64 + r) * DIM + d0);
    const float4 a = *reinterpret_cast<const float4*>(src);
    const float4 b = *reinterpret_cast<const float4*>(src + 4);
    u16x8 o;
    o[0] = (u16)f2bf(a.x); o[1] = (u16)f2bf(a.y); o[2] = (u16)f2bf(a.z); o[3] = (u16)f2bf(a.w);
    o[4] = (u16)f2bf(b.x); o[5] = (u16)f2bf(b.y); o[6] = (u16)f2bf(b.z); o[7] = (u16)f2bf(b.w);
    *reinterpret_cast<u16x8*>(Kp + (size_t)idx * 8) = o;
}

// ---------- pre-kernel: V f32 -> bf16 transposed (V^T[d][key]) + swizzled ----------
__global__ __launch_bounds__(256)
void conv_v_kernel(const float* __restrict__ V, u16* __restrict__ Vp)
{
    __shared__ float tile[64][65];
    const int tid = (int)threadIdx.x;
    const int h   = (int)blockIdx.x >> 5;
    const int kt  = (int)blockIdx.x & 31;

    const int row0 = tid >> 4;
    const int c0   = (tid & 15) << 2;
    #pragma unroll
    for (int i = 0; i < 4; ++i) {
        const int row = row0 + (i << 4);
        const float4 v = *reinterpret_cast<const float4*>(
            V + (((size_t)h * SEQ + (size_t)kt * 64 + row) * DIM + c0));
        tile[row][c0 + 0] = v.x; tile[row][c0 + 1] = v.y;
        tile[row][c0 + 2] = v.z; tile[row][c0 + 3] = v.w;
    }
    __syncthreads();

    #pragma unroll
    for (int i = 0; i < 2; ++i) {
        const int oi = tid + i * 256;         // rd*8 + u
        const int u  = oi & 7;
        const int rd = oi >> 3;               // output row = d
        const int k0 = ((u ^ (rd & 7)) << 3); // plain key octet
        u16x8 o;
        #pragma unroll
        for (int j = 0; j < 8; ++j)
            o[j] = (u16)f2bf(tile[k0 + j][rd]);
        *reinterpret_cast<u16x8*>(Vp + ((size_t)((h * 32 + kt) * 512 + oi)) * 8) = o;
    }
}

// ---------- main fused kernel ----------
__global__ __launch_bounds__(256, 4)
void sdpa_main_kernel(const float* __restrict__ Qp, const u16* __restrict__ Kp,
                      const u16* __restrict__ Vp, const int* __restrict__ Mp,
                      float* __restrict__ Op, float* __restrict__ Pg_)
{
    __shared__ short Qs[BQ][PADK];
    __shared__ u16   Ks[64 * 64];   // linear, swizzled rows
    __shared__ u16   Vs[64 * 64];   // V^T tile, linear, swizzled rows
    __shared__ short Ps[BQ][PADK];

    const int tid  = (int)threadIdx.x;
    const int lane = tid & 63;
    const int w    = tid >> 6;
    const int mrow = lane & 15;
    const int kgrp = (lane >> 4) << 2;

    const int qt = (int)blockIdx.x;
    const int bh = (int)blockIdx.y;

    const size_t headoff = (size_t)bh * SEQ * DIM;
    const float* Qg = Qp + headoff + (size_t)qt * BQ * DIM;
    const u16*   Kh = Kp + (size_t)bh * NKT * 4096;   // per-kt tiles of 4096 u16
    const u16*   Vh = Vp + (size_t)bh * NKT * 4096;
    const int*   Mg = Mp + (size_t)(bh / NH) * SEQ;
    float*       Og = Op + headoff + (size_t)qt * BQ * DIM;
    float*       Pg = Pg_ + ((size_t)bh * SEQ + (size_t)qt * BQ) * SEQ;

    const int r0 = tid >> 4;
    const int c0 = (tid & 15) << 2;

    // stage Q (once): f32 -> bf16 with scale folded
    #pragma unroll
    for (int i = 0; i < 4; ++i) {
        const int row = r0 + (i << 4);
        const float4 v = *reinterpret_cast<const float4*>(Qg + row * DIM + c0);
        s16x4 s;
        s[0] = f2bf(v.x * QSCALE); s[1] = f2bf(v.y * QSCALE);
        s[2] = f2bf(v.z * QSCALE); s[3] = f2bf(v.w * QSCALE);
        *reinterpret_cast<s16x4*>(&Qs[row][c0]) = s;
    }
    __syncthreads();

    const bf16x8 qf0 = ldfrag_pad(&Qs[w * 16 + mrow][0], kgrp);
    const bf16x8 qf1 = ldfrag_pad(&Qs[w * 16 + mrow][0], 32 + kgrp);

    // ===== pass 1: row sums =====
    float lsum[4] = {0.f, 0.f, 0.f, 0.f};

    for (int kt = 0; kt < NKT; ++kt) {
        __syncthreads();
        {
            const u16* g = Kh + (size_t)kt * 4096;
            const int o0 = tid * 8, o1 = tid * 8 + 2048;
            const u16x8 a = *reinterpret_cast<const u16x8*>(g + o0);
            const u16x8 b = *reinterpret_cast<const u16x8*>(g + o1);
            *reinterpret_cast<u16x8*>(&Ks[o0]) = a;
            *reinterpret_cast<u16x8*>(&Ks[o1]) = b;
        }
        __syncthreads();

        const int k0 = kt * BK;
        #pragma unroll
        for (int t = 0; t < 4; ++t) {
            const bf16x8 kf0 = ldfrag_swz(Ks, t * 16 + mrow, kgrp);
            const bf16x8 kf1 = ldfrag_swz(Ks, t * 16 + mrow, 32 + kgrp);
            f32x4 acc = {0.f, 0.f, 0.f, 0.f};
            acc = __builtin_amdgcn_mfma_f32_16x16x32_bf16(qf0, kf0, acc, 0, 0, 0);
            acc = __builtin_amdgcn_mfma_f32_16x16x32_bf16(qf1, kf1, acc, 0, 0, 0);
            const float mz = Mg[k0 + t * 16 + mrow] ? 0.f : 1.f;
            #pragma unroll
            for (int r = 0; r < 4; ++r)
                lsum[r] += mz * __builtin_amdgcn_exp2f(acc[r]);
        }
    }

    float rinv[4];
    #pragma unroll
    for (int r = 0; r < 4; ++r) {
        float v = lsum[r];
        v += __shfl_xor(v, 1);
        v += __shfl_xor(v, 2);
        v += __shfl_xor(v, 4);
        v += __shfl_xor(v, 8);
        rinv[r] = 1.0f / v;
    }

    // ===== pass 2: P write + O accumulate =====
    f32x4 oacc[4];
    #pragma unroll
    for (int n = 0; n < 4; ++n) {
        oacc[n][0] = 0.f; oacc[n][1] = 0.f; oacc[n][2] = 0.f; oacc[n][3] = 0.f;
    }

    for (int kt = 0; kt < NKT; ++kt) {
        __syncthreads();
        {
            const u16* gk = Kh + (size_t)kt * 4096;
            const u16* gv = Vh + (size_t)kt * 4096;
            const int o0 = tid * 8, o1 = tid * 8 + 2048;
            const u16x8 a = *reinterpret_cast<const u16x8*>(gk + o0);
            const u16x8 b = *reinterpret_cast<const u16x8*>(gk + o1);
            const u16x8 c = *reinterpret_cast<const u16x8*>(gv + o0);
            const u16x8 d = *reinterpret_cast<const u16x8*>(gv + o1);
            *reinterpret_cast<u16x8*>(&Ks[o0]) = a;
            *reinterpret_cast<u16x8*>(&Ks[o1]) = b;
            *reinterpret_cast<u16x8*>(&Vs[o0]) = c;
            *reinterpret_cast<u16x8*>(&Vs[o1]) = d;
        }
        __syncthreads();

        const int k0 = kt * BK;
        #pragma unroll
        for (int t = 0; t < 4; ++t) {
            const bf16x8 kf0 = ldfrag_swz(Ks, t * 16 + mrow, kgrp);
            const bf16x8 kf1 = ldfrag_swz(Ks, t * 16 + mrow, 32 + kgrp);
            f32x4 acc = {0.f, 0.f, 0.f, 0.f};
            acc = __builtin_amdgcn_mfma_f32_16x16x32_bf16(qf0, kf0, acc, 0, 0, 0);
            acc = __builtin_amdgcn_mfma_f32_16x16x32_bf16(qf1, kf1, acc, 0, 0, 0);
            const int gkey = k0 + t * 16 + mrow;
            const float mz = Mg[gkey] ? 0.f : 1.f;
            #pragma unroll
            for (int r = 0; r < 4; ++r) {
                const float p = mz * __builtin_amdgcn_exp2f(acc[r]) * rinv[r];
                Ps[w * 16 + kgrp + r][t * 16 + mrow] = f2bf(p);
                Pg[(size_t)(w * 16 + kgrp + r) * SEQ + gkey] = p;
            }
        }

        // P rows of this wave written only by this wave -> no barrier needed
        const bf16x8 pf0 = ldfrag_pad(&Ps[w * 16 + mrow][0], kgrp);
        const bf16x8 pf1 = ldfrag_pad(&Ps[w * 16 + mrow][0], 32 + kgrp);
        #pragma unroll
        for (int n = 0; n < 4; ++n) {
            const bf16x8 vf0 = ldfrag_swz(Vs, n * 16 + mrow, kgrp);
            const bf16x8 vf1 = ldfrag_swz(Vs, n * 16 + mrow, 32 + kgrp);
            oacc[n] = __builtin_amdgcn_mfma_f32_16x16x32_bf16(pf0, vf0, oacc[n], 0, 0, 0);
            oacc[n] = __builtin_amdgcn_mfma_f32_16x16x32_bf16(pf1, vf1, oacc[n], 0, 0, 0);
        }
    }

    #pragma unroll
    for (int n = 0; n < 4; ++n) {
        #pragma unroll
        for (int r = 0; r < 4; ++r)
            Og[(size_t)(w * 16 + kgrp + r) * DIM + n * 16 + mrow] = oacc[n][r];
    }
}

extern "C" void kernel_launch(void* const* d_in, const int* in_sizes, int n_in,
                              void* d_out, int out_size, void* d_ws, size_t ws_size,
                              hipStream_t stream) {
    const float* Q = (const float*)d_in[0];
    const float* K = (const float*)d_in[1];
    const float* V = (const float*)d_in[2];
    const int*   M = (const int*)d_in[3];
    float* O = (float*)d_out;
    float* P = O + (size_t)NB * NH * SEQ * DIM;

    u16* Kp = (u16*)d_ws;                                   // 8 MB
    u16* Vp = Kp + (size_t)NHEAD * SEQ * DIM;               // 8 MB

    conv_k_kernel<<<dim3(NHEAD * NKT * 64 * 8 / 256), dim3(256), 0, stream>>>(K, Kp);
    conv_v_kernel<<<dim3(NHEAD * NKT), dim3(256), 0, stream>>>(V, Vp);

    dim3 grid(SEQ / BQ, NB * NH);
    sdpa_main_kernel<<<grid, dim3(256, 1, 1), 0, stream>>>(Q, Kp, Vp, M, O, P);
}